// Round 14
// baseline (235.495 us; speedup 1.0000x reference)
//
#include <hip/hip_runtime.h>
#include <hip/hip_bf16.h>
#include <cstdint>

typedef __bf16 bf16_t;
typedef __attribute__((ext_vector_type(8))) __bf16 bf16x8;
typedef __attribute__((ext_vector_type(4))) __bf16 bf16x4;
typedef __attribute__((ext_vector_type(2))) __bf16 bf16x2;
typedef __attribute__((ext_vector_type(4))) float f32x4;

#define GLOBAL_AS __attribute__((address_space(1)))
#define LDS_AS __attribute__((address_space(3)))

__device__ __forceinline__ void lds_load16(void* lds, const void* g) {
    __builtin_amdgcn_global_load_lds((GLOBAL_AS void*)g, (LDS_AS void*)lds, 16, 0, 0);
}

// ---------------- fused prep: weight transposes + x cast + bias concat ----------------
__global__ __launch_bounds__(256) void prep_all(const float* __restrict__ x,
                                                const float* __restrict__ Wq,
                                                const float* __restrict__ Wk,
                                                const float* __restrict__ Wv,
                                                const float* __restrict__ Wo,
                                                const float* __restrict__ W1,
                                                const float* __restrict__ W2,
                                                const float* __restrict__ bq,
                                                const float* __restrict__ bk,
                                                const float* __restrict__ bv,
                                                bf16_t* __restrict__ xb,
                                                bf16_t* __restrict__ WqkvT,
                                                bf16_t* __restrict__ WoT,
                                                bf16_t* __restrict__ W1T,
                                                bf16_t* __restrict__ W2T,
                                                float* __restrict__ qkvb) {
    __shared__ float T[64][65];
    const int bid = blockIdx.x, tid = threadIdx.x;
    if (bid < 3072) {
        const float* W; bf16_t* WT; int Kd, Nd, lb;
        if (bid < 1024) {
            Kd = 1024; Nd = 1024; lb = bid & 255;
            const int w = bid >> 8;
            W  = (w == 0) ? Wq : (w == 1) ? Wk : (w == 2) ? Wv : Wo;
            WT = (w == 0) ? WqkvT : (w == 1) ? WqkvT + 1048576
               : (w == 2) ? WqkvT + 2097152 : WoT;
        } else if (bid < 2048) { W = W1; WT = W1T; Kd = 1024; Nd = 4096; lb = bid - 1024; }
        else                   { W = W2; WT = W2T; Kd = 4096; Nd = 1024; lb = bid - 2048; }
        const int nbk = Kd >> 6;
        const int bk = lb % nbk, bn = lb / nbk;
        const int k0 = bk << 6, n0 = bn << 6;
        #pragma unroll
        for (int rep = 0; rep < 4; ++rep) {
            int r = rep * 16 + (tid >> 4);
            int c = (tid & 15) * 4;
            float4 v = *(const float4*)(W + (size_t)(k0 + r) * Nd + n0 + c);
            T[r][c] = v.x; T[r][c + 1] = v.y; T[r][c + 2] = v.z; T[r][c + 3] = v.w;
        }
        __syncthreads();
        #pragma unroll
        for (int rep = 0; rep < 4; ++rep) {
            int r = rep * 16 + (tid >> 4);   // n-local
            int c = (tid & 15) * 4;          // k-local
            bf16x4 o;
            o[0] = (bf16_t)T[c][r]; o[1] = (bf16_t)T[c + 1][r];
            o[2] = (bf16_t)T[c + 2][r]; o[3] = (bf16_t)T[c + 3][r];
            *(bf16x4*)(WT + (size_t)(n0 + r) * Kd + k0 + c) = o;
        }
    } else if (bid < 7168) {
        const int i = (bid - 3072) * 256 + tid;   // < 1048576
        float4 v = *(const float4*)(x + (size_t)i * 4);
        bf16x4 o;
        o[0] = (bf16_t)v.x; o[1] = (bf16_t)v.y; o[2] = (bf16_t)v.z; o[3] = (bf16_t)v.w;
        *(bf16x4*)(xb + (size_t)i * 4) = o;
    } else {
        const int i = (bid - 7168) * 256 + tid;
        if (i < 3072)
            qkvb[i] = (i < 1024) ? bq[i] : (i < 2048) ? bk[i - 1024] : bv[i - 2048];
    }
}

// ---------------- 256x256 phase-split GEMM: C = A[M][K] @ Bt[N][K]^T + bias ----------------
// BM=BN=256, BK=64, 8 waves. Counted-vmcnt ledger (see round-5 comment).
// OM: 0 = bf16 full output, 1 = f32 split-K partials, 2 = bf16 split-K partials.
template <int OM, bool RELU>
__global__ __launch_bounds__(512, 2) void gemm256(const bf16_t* __restrict__ A,
                                                  const bf16_t* __restrict__ Bt,
                                                  const float* __restrict__ bias,
                                                  void* __restrict__ Cv,
                                                  int M, int N, int K,
                                                  int kc_len, int n_kc) {
    __shared__ alignas(16) bf16_t As[2][256 * 64];
    __shared__ alignas(16) bf16_t Bs[2][256 * 64];
    const int tid = threadIdx.x;
    const int wid = tid >> 6, lane = tid & 63;
    const int lr = lane & 15, lg = lane >> 4;
    const int wr = wid >> 2, wc = wid & 3;
    const int lrsw = (lr & 7) << 4;

    const int nbn = N >> 8;
    const int nbase = (M >> 8) * nbn;
    const int nwg = nbase * n_kc;
    int bid = blockIdx.x;
    int wg;
    if ((nwg & 7) == 0) { int q = nwg >> 3; wg = (bid & 7) * q + (bid >> 3); }
    else wg = bid;
    const int kc = wg / nbase;
    const int inner = wg - kc * nbase;
    const int bm = inner / nbn, bn = inner % nbn;

    f32x4 acc[8][4];
    #pragma unroll
    for (int i = 0; i < 8; ++i)
        #pragma unroll
        for (int j = 0; j < 4; ++j) acc[i][j] = f32x4{0.f, 0.f, 0.f, 0.f};

    const int srow = wid * 16 + (lane >> 3);
    const int colbyte = (((lane & 7) ^ (lane >> 3)) << 4);
    const char* gA = (const char*)(A + ((size_t)(bm * 256 + srow) * K + kc * kc_len)) + colbyte;
    const char* gB = (const char*)(Bt + ((size_t)(bn * 256 + srow) * K + kc * kc_len)) + colbyte;
    const size_t rs8 = (size_t)8 * K * 2;
    const size_t rs128 = (size_t)128 * K * 2;

    auto stA = [&](int b, int half, int kt) {
        char* d = (char*)As[b] + (half * 128 + wid * 16) * 128;
        const char* s = gA + (size_t)half * rs128 + (size_t)kt * 128;
        lds_load16(d, s);
        lds_load16(d + 1024, s + rs8);
    };
    auto stB = [&](int b, int half, int kt) {
        char* d = (char*)Bs[b] + (half * 128 + wid * 16) * 128;
        const char* s = gB + (size_t)half * rs128 + (size_t)kt * 128;
        lds_load16(d, s);
        lds_load16(d + 1024, s + rs8);
    };
    auto ldA = [&](int b, int m, int kk) {
        const int row = (m >> 2) * 128 + (m & 3) * 32 + wr * 16 + lr;
        return *(const bf16x8*)((const char*)As[b] + row * 128 + ((kk * 64 + lg * 16) ^ lrsw));
    };
    auto ldB = [&](int b, int n, int kk) {
        const int row = n * 64 + wc * 16 + lr;
        return *(const bf16x8*)((const char*)Bs[b] + row * 128 + ((kk * 64 + lg * 16) ^ lrsw));
    };

    const int NT = kc_len >> 6;
    stA(0, 0, 0); stB(0, 0, 0); stB(0, 1, 0); stA(0, 1, 0);
    asm volatile("s_waitcnt vmcnt(4)" ::: "memory");
    __builtin_amdgcn_s_barrier();

    bf16x8 afr[4][2], bfr[4][2];
    #pragma unroll 1
    for (int kt = 0; kt < NT; ++kt) {
        const int buf = kt & 1;
        const int ktn = (kt + 1 < NT) ? kt + 1 : kt;

        // ---- phase 0: (0,0); reads A-half0 + B n0,n1 ----
        #pragma unroll
        for (int m = 0; m < 4; ++m) {
            afr[m][0] = ldA(buf, m, 0);
            afr[m][1] = ldA(buf, m, 1);
        }
        #pragma unroll
        for (int n = 0; n < 2; ++n) {
            bfr[n][0] = ldB(buf, n, 0);
            bfr[n][1] = ldB(buf, n, 1);
        }
        stA(buf ^ 1, 0, ktn);
        __builtin_amdgcn_s_barrier();
        __builtin_amdgcn_s_setprio(1);
        #pragma unroll
        for (int m = 0; m < 4; ++m)
            #pragma unroll
            for (int n = 0; n < 2; ++n) {
                acc[m][n] = __builtin_amdgcn_mfma_f32_16x16x32_bf16(afr[m][0], bfr[n][0], acc[m][n], 0, 0, 0);
                acc[m][n] = __builtin_amdgcn_mfma_f32_16x16x32_bf16(afr[m][1], bfr[n][1], acc[m][n], 0, 0, 0);
            }
        __builtin_amdgcn_s_setprio(0);
        asm volatile("s_waitcnt vmcnt(4)" ::: "memory");
        __builtin_amdgcn_s_barrier();

        // ---- phase 1: (0,1); reads B n2,n3 ----
        #pragma unroll
        for (int n = 2; n < 4; ++n) {
            bfr[n][0] = ldB(buf, n, 0);
            bfr[n][1] = ldB(buf, n, 1);
        }
        stB(buf ^ 1, 0, ktn);
        __builtin_amdgcn_s_barrier();
        __builtin_amdgcn_s_setprio(1);
        #pragma unroll
        for (int m = 0; m < 4; ++m)
            #pragma unroll
            for (int n = 2; n < 4; ++n) {
                acc[m][n] = __builtin_amdgcn_mfma_f32_16x16x32_bf16(afr[m][0], bfr[n][0], acc[m][n], 0, 0, 0);
                acc[m][n] = __builtin_amdgcn_mfma_f32_16x16x32_bf16(afr[m][1], bfr[n][1], acc[m][n], 0, 0, 0);
            }
        __builtin_amdgcn_s_setprio(0);
        asm volatile("s_waitcnt vmcnt(4)" ::: "memory");
        __builtin_amdgcn_s_barrier();

        // ---- phase 2: (1,0); reads A-half1 ----
        #pragma unroll
        for (int m = 0; m < 4; ++m) {
            afr[m][0] = ldA(buf, m + 4, 0);
            afr[m][1] = ldA(buf, m + 4, 1);
        }
        stB(buf ^ 1, 1, ktn);
        __builtin_amdgcn_s_barrier();
        __builtin_amdgcn_s_setprio(1);
        #pragma unroll
        for (int m = 0; m < 4; ++m)
            #pragma unroll
            for (int n = 0; n < 2; ++n) {
                acc[m + 4][n] = __builtin_amdgcn_mfma_f32_16x16x32_bf16(afr[m][0], bfr[n][0], acc[m + 4][n], 0, 0, 0);
                acc[m + 4][n] = __builtin_amdgcn_mfma_f32_16x16x32_bf16(afr[m][1], bfr[n][1], acc[m + 4][n], 0, 0, 0);
            }
        __builtin_amdgcn_s_setprio(0);
        __builtin_amdgcn_s_barrier();

        // ---- phase 3: (1,1) ----
        stA(buf ^ 1, 1, ktn);
        __builtin_amdgcn_s_barrier();
        __builtin_amdgcn_s_setprio(1);
        #pragma unroll
        for (int m = 0; m < 4; ++m)
            #pragma unroll
            for (int n = 2; n < 4; ++n) {
                acc[m + 4][n] = __builtin_amdgcn_mfma_f32_16x16x32_bf16(afr[m][0], bfr[n][0], acc[m + 4][n], 0, 0, 0);
                acc[m + 4][n] = __builtin_amdgcn_mfma_f32_16x16x32_bf16(afr[m][1], bfr[n][1], acc[m + 4][n], 0, 0, 0);
            }
        __builtin_amdgcn_s_setprio(0);
        asm volatile("s_waitcnt vmcnt(4)" ::: "memory");
        __builtin_amdgcn_s_barrier();
    }

    // epilogue
    float* outf = (float*)Cv + (size_t)kc * M * N;
    bf16_t* outb = (bf16_t*)Cv + (size_t)kc * M * N;
    float bv[4];
    #pragma unroll
    for (int n = 0; n < 4; ++n) {
        const int c = (bn << 8) + n * 64 + wc * 16 + lr;
        bv[n] = (bias && kc == 0) ? bias[c] : 0.f;
    }
    #pragma unroll
    for (int m = 0; m < 8; ++m) {
        const int row0 = (bm << 8) + (m >> 2) * 128 + (m & 3) * 32 + wr * 16 + (lg << 2);
        #pragma unroll
        for (int n = 0; n < 4; ++n) {
            const int c = (bn << 8) + n * 64 + wc * 16 + lr;
            #pragma unroll
            for (int j = 0; j < 4; ++j) {
                float v = acc[m][n][j] + bv[n];
                if (RELU) v = fmaxf(v, 0.f);
                if (OM == 0)      ((bf16_t*)Cv)[(size_t)(row0 + j) * N + c] = (bf16_t)v;
                else if (OM == 1) outf[(size_t)(row0 + j) * N + c] = v;
                else              outb[(size_t)(row0 + j) * N + c] = (bf16_t)v;
            }
        }
    }
}

// ---------------- V-transpose only: QKV[4096][3072] V-part -> VT [32][64][2048] ----------------
__global__ __launch_bounds__(256) void reshape_v(const bf16_t* __restrict__ QKV,
                                                 bf16_t* __restrict__ VT) {
    __shared__ alignas(16) bf16_t Vl[64][72];
    const int n = blockIdx.x >> 5, st = blockIdx.x & 31;
    const int b = n >> 4, h = n & 15;
    const int s0 = st << 6;
    const int tid = threadIdx.x;

    #pragma unroll
    for (int rep = 0; rep < 2; ++rep) {
        int chunk = rep * 256 + tid;
        int sl = chunk >> 3, c8 = (chunk & 7) << 3;
        size_t srow = (size_t)(s0 + sl) * 2 + b;
        *(bf16x8*)&Vl[sl][c8] = *(const bf16x8*)(QKV + srow * 3072 + 2048 + h * 64 + c8);
    }
    __syncthreads();
    #pragma unroll
    for (int rep = 0; rep < 2; ++rep) {
        int chunk = rep * 256 + tid;
        int d = chunk >> 3, c8 = (chunk & 7) << 3;
        bf16x8 v;
        #pragma unroll
        for (int e = 0; e < 8; ++e) v[e] = Vl[c8 + e][d];
        *(bf16x8*)(VT + ((size_t)n * 64 + d) * 2048 + s0 + c8) = v;
    }
}

// ---------------- flash attention, split-S x2: each block does half the t-range ----------------
// Round-13 proven inner loop (K/V LDS dbuf, stage-before-vmcnt(4), 2 barriers/
// tile, b64 P-writes, setprio). Constant shift m=12 makes partials EXACTLY
// additive: block (n,qt,sp) accumulates un-normalized O (f32) and l over
// t in [sp*1024, sp*1024+1024); combine_o sums halves and normalizes.
__global__ __launch_bounds__(256) void attn_fwd(const bf16_t* __restrict__ QKV,
                                                const bf16_t* __restrict__ VT,
                                                float* __restrict__ Opart,
                                                float* __restrict__ lpart) {
    const int S = 2048;
    const int n = blockIdx.x >> 5;               // b*16 + h
    const int qt = (blockIdx.x >> 1) & 15;
    const int sp = blockIdx.x & 1;
    const int q0 = qt << 7;                      // 128 q-rows per block
    const int b = n >> 4, h = n & 15;
    const int tid = threadIdx.x, wid = tid >> 6, lane = tid & 63;
    const int lr = lane & 15, lg = lane >> 4;
    const int lrsw = (lr & 7) << 4;

    __shared__ alignas(16) bf16_t Ks[2][64 * 64];
    __shared__ alignas(16) bf16_t Vs[2][64 * 64];
    __shared__ alignas(16) bf16_t Ps[4][2][16 * 64];

    char* pbs0 = (char*)&Ps[wid][0][0];
    char* pbs1 = (char*)&Ps[wid][1][0];

    // Q fragments straight from QKV (token-major), scaled in registers
    const float qsc = 0.125f * 1.4426950408889634f;
    auto scale8 = [&](bf16x8 v) {
        bf16x8 r;
        #pragma unroll
        for (int e = 0; e < 8; ++e) r[e] = (bf16_t)((float)v[e] * qsc);
        return r;
    };
    const bf16_t* Qrow0 = QKV + ((size_t)(q0 + wid * 32 + lr) * 2 + b) * 3072 + h * 64;
    const bf16_t* Qrow1 = Qrow0 + (size_t)16 * 2 * 3072;
    const bf16x8 qa0 = scale8(*(const bf16x8*)(Qrow0 + lg * 8));
    const bf16x8 qa1 = scale8(*(const bf16x8*)(Qrow0 + 32 + lg * 8));
    const bf16x8 qb0 = scale8(*(const bf16x8*)(Qrow1 + lg * 8));
    const bf16x8 qb1 = scale8(*(const bf16x8*)(Qrow1 + 32 + lg * 8));

    bf16x8 ones;
    #pragma unroll
    for (int e = 0; e < 8; ++e) ones[e] = (bf16_t)1.0f;

    const int colbyte = (((lane & 7) ^ (lane >> 3)) << 4);
    const int tbase = sp << 10;                  // this block's t-range start
    // K source in QKV: row t at byte stride 2*3072*2 = 12288
    const size_t kstride = (size_t)2 * 3072 * 2;
    const char* ksrc0 = (const char*)QKV +
        (((size_t)(tbase + wid * 16 + (lane >> 3)) * 2 + b) * 3072 + 1024 + h * 64) * 2 + colbyte;
    const char* ksrc1 = ksrc0 + 8 * kstride;
    const char* vsrc0 = (const char*)(VT + ((size_t)n * 64 + wid * 16 + (lane >> 3)) * S + tbase) + colbyte;
    const char* vsrc1 = vsrc0 + (size_t)8 * S * 2;

    auto stage = [&](int bf, int t0) {   // t0 is local to this block's range
        lds_load16((char*)Ks[bf] + wid * 2048,        ksrc0 + (size_t)t0 * kstride);
        lds_load16((char*)Ks[bf] + wid * 2048 + 1024, ksrc1 + (size_t)t0 * kstride);
        lds_load16((char*)Vs[bf] + wid * 2048,        vsrc0 + (size_t)t0 * 2);
        lds_load16((char*)Vs[bf] + wid * 2048 + 1024, vsrc1 + (size_t)t0 * 2);
    };

    f32x4 oaccA[4], oaccB[4];
    #pragma unroll
    for (int i = 0; i < 4; ++i) {
        oaccA[i] = f32x4{0.f, 0.f, 0.f, 0.f};
        oaccB[i] = f32x4{0.f, 0.f, 0.f, 0.f};
    }
    f32x4 laccA = f32x4{0.f, 0.f, 0.f, 0.f};
    f32x4 laccB = f32x4{0.f, 0.f, 0.f, 0.f};

    stage(0, 0);
    int buf = 0;

    #pragma unroll 1
    for (int t0 = 0; t0 < 1024; t0 += 64) {
        if (t0 + 64 < 1024) {
            stage(buf ^ 1, t0 + 64);
            asm volatile("s_waitcnt vmcnt(4)" ::: "memory");
        } else {
            asm volatile("s_waitcnt vmcnt(0)" ::: "memory");
        }
        __builtin_amdgcn_s_barrier();

        const char* kb = (char*)Ks[buf];
        const char* vb = (char*)Vs[buf];

        // S^T tiles for both q-groups; K-frags loaded once, used twice
        f32x4 swA[4], swB[4];
        __builtin_amdgcn_s_setprio(1);
        #pragma unroll
        for (int tc = 0; tc < 4; ++tc) {
            const char* krow = kb + (tc * 16 + lr) * 128;
            bf16x8 kf0 = *(const bf16x8*)(krow + ((lg * 16) ^ lrsw));
            bf16x8 kf1 = *(const bf16x8*)(krow + ((64 + lg * 16) ^ lrsw));
            f32x4 za = f32x4{-12.f, -12.f, -12.f, -12.f};
            za = __builtin_amdgcn_mfma_f32_16x16x32_bf16(kf0, qa0, za, 0, 0, 0);
            za = __builtin_amdgcn_mfma_f32_16x16x32_bf16(kf1, qa1, za, 0, 0, 0);
            swA[tc] = za;
            f32x4 zb = f32x4{-12.f, -12.f, -12.f, -12.f};
            zb = __builtin_amdgcn_mfma_f32_16x16x32_bf16(kf0, qb0, zb, 0, 0, 0);
            zb = __builtin_amdgcn_mfma_f32_16x16x32_bf16(kf1, qb1, zb, 0, 0, 0);
            swB[tc] = zb;
        }
        __builtin_amdgcn_s_setprio(0);

        // P = exp2(shifted score), both groups (independent chains)
        #pragma unroll
        for (int tc = 0; tc < 4; ++tc)
            #pragma unroll
            for (int j = 0; j < 4; ++j) {
                swA[tc][j] = __builtin_amdgcn_exp2f(swA[tc][j]);
                swB[tc][j] = __builtin_amdgcn_exp2f(swB[tc][j]);
            }

        // pack P^T into per-wave-per-group LDS (swizzled), b64 writes
        #pragma unroll
        for (int tc = 0; tc < 4; ++tc) {
            bf16x4 pa, pb;
            pa[0] = (bf16_t)swA[tc][0]; pa[1] = (bf16_t)swA[tc][1];
            pa[2] = (bf16_t)swA[tc][2]; pa[3] = (bf16_t)swA[tc][3];
            pb[0] = (bf16_t)swB[tc][0]; pb[1] = (bf16_t)swB[tc][1];
            pb[2] = (bf16_t)swB[tc][2]; pb[3] = (bf16_t)swB[tc][3];
            const int off = (tc * 32 + lg * 8) ^ lrsw;
            *(bf16x4*)(pbs0 + lr * 128 + off) = pa;
            *(bf16x4*)(pbs1 + lr * 128 + off) = pb;
        }
        bf16x8 pA0 = *(const bf16x8*)(pbs0 + lr * 128 + ((lg * 16) ^ lrsw));
        bf16x8 pA1 = *(const bf16x8*)(pbs0 + lr * 128 + ((64 + lg * 16) ^ lrsw));
        bf16x8 pB0 = *(const bf16x8*)(pbs1 + lr * 128 + ((lg * 16) ^ lrsw));
        bf16x8 pB1 = *(const bf16x8*)(pbs1 + lr * 128 + ((64 + lg * 16) ^ lrsw));

        // l row-sums + PV on the MFMA pipe (setprio cluster)
        __builtin_amdgcn_s_setprio(1);
        laccA = __builtin_amdgcn_mfma_f32_16x16x32_bf16(ones, pA0, laccA, 0, 0, 0);
        laccA = __builtin_amdgcn_mfma_f32_16x16x32_bf16(ones, pA1, laccA, 0, 0, 0);
        laccB = __builtin_amdgcn_mfma_f32_16x16x32_bf16(ones, pB0, laccB, 0, 0, 0);
        laccB = __builtin_amdgcn_mfma_f32_16x16x32_bf16(ones, pB1, laccB, 0, 0, 0);

        // O^T += V^T @ P^T ; V-frags loaded once, used by both groups
        #pragma unroll
        for (int vc = 0; vc < 4; ++vc) {
            const char* vrow = vb + (vc * 16 + lr) * 128;
            bf16x8 vf0 = *(const bf16x8*)(vrow + ((lg * 16) ^ lrsw));
            bf16x8 vf1 = *(const bf16x8*)(vrow + ((64 + lg * 16) ^ lrsw));
            oaccA[vc] = __builtin_amdgcn_mfma_f32_16x16x32_bf16(vf0, pA0, oaccA[vc], 0, 0, 0);
            oaccA[vc] = __builtin_amdgcn_mfma_f32_16x16x32_bf16(vf1, pA1, oaccA[vc], 0, 0, 0);
            oaccB[vc] = __builtin_amdgcn_mfma_f32_16x16x32_bf16(vf0, pB0, oaccB[vc], 0, 0, 0);
            oaccB[vc] = __builtin_amdgcn_mfma_f32_16x16x32_bf16(vf1, pB1, oaccB[vc], 0, 0, 0);
        }
        __builtin_amdgcn_s_setprio(0);
        __builtin_amdgcn_s_barrier();
        buf ^= 1;
    }

    // epilogue: un-normalized O partial (f32) + l partial
    const int qrowA = q0 + wid * 32 + lr;
    const int qrowB = qrowA + 16;
    float* Op = Opart + (size_t)sp * 4096 * 1024;
    const size_t tokA = (size_t)qrowA * 2 + b;
    const size_t tokB = (size_t)qrowB * 2 + b;
    #pragma unroll
    for (int vc = 0; vc < 4; ++vc) {
        f32x4 oa = oaccA[vc], ob = oaccB[vc];
        *(f32x4*)(Op + tokA * 1024 + h * 64 + vc * 16 + lg * 4) = oa;
        *(f32x4*)(Op + tokB * 1024 + h * 64 + vc * 16 + lg * 4) = ob;
    }
    if (lg == 0) {
        lpart[(size_t)sp * 65536 + n * 2048 + qrowA] = laccA[0];
        lpart[(size_t)sp * 65536 + n * 2048 + qrowB] = laccB[0];
    }
}

// ---------------- combine split-S halves: Otok = (O0+O1) / (l0+l1) ----------------
__global__ __launch_bounds__(256) void combine_o(const float* __restrict__ Opart,
                                                 const float* __restrict__ lpart,
                                                 bf16_t* __restrict__ O) {
    const int tok = blockIdx.x, tid = threadIdx.x;
    const int c = tid * 4;
    const int h = c >> 6;
    const int q = tok >> 1, b = tok & 1;
    const int n = b * 16 + h;
    const float l = lpart[n * 2048 + q] + lpart[65536 + n * 2048 + q];
    const float inv = 1.0f / l;
    const size_t base = (size_t)tok * 1024 + c;
    float4 a = *(const float4*)(Opart + base);
    float4 d = *(const float4*)(Opart + (size_t)4096 * 1024 + base);
    bf16x4 o;
    o[0] = (bf16_t)((a.x + d.x) * inv);
    o[1] = (bf16_t)((a.y + d.y) * inv);
    o[2] = (bf16_t)((a.z + d.z) * inv);
    o[3] = (bf16_t)((a.w + d.w) * inv);
    *(bf16x4*)(O + base) = o;
}

// ---------------- residual + LayerNorm: out = LN(X + sum_p Y_p)*g + b ----------------
// X is bf16 (residual path); partials Y are bf16 (written by gemm256 OM=2).
template <int P>
__global__ __launch_bounds__(256) void ln_res(const bf16_t* __restrict__ X,
                                              const bf16_t* __restrict__ Y,
                                              const float* __restrict__ g,
                                              const float* __restrict__ be,
                                              float* __restrict__ outf,
                                              bf16_t* __restrict__ outb) {
    const int row = blockIdx.x, tid = threadIdx.x;
    const size_t base = (size_t)row * 1024 + tid * 4;
    const size_t pstride = (size_t)4096 * 1024;
    bf16x4 xv = *(const bf16x4*)(X + base);
    float v0 = (float)xv[0], v1 = (float)xv[1], v2 = (float)xv[2], v3 = (float)xv[3];
    #pragma unroll
    for (int p = 0; p < P; ++p) {
        bf16x4 yv = *(const bf16x4*)(Y + p * pstride + base);
        v0 += (float)yv[0]; v1 += (float)yv[1]; v2 += (float)yv[2]; v3 += (float)yv[3];
    }
    float s = v0 + v1 + v2 + v3;
    float sq = v0 * v0 + v1 * v1 + v2 * v2 + v3 * v3;
    #pragma unroll
    for (int m = 1; m < 64; m <<= 1) {
        s += __shfl_xor(s, m);
        sq += __shfl_xor(sq, m);
    }
    __shared__ float rs[4], rq[4];
    const int wid = tid >> 6;
    if ((tid & 63) == 0) { rs[wid] = s; rq[wid] = sq; }
    __syncthreads();
    s = rs[0] + rs[1] + rs[2] + rs[3];
    sq = rq[0] + rq[1] + rq[2] + rq[3];
    const float mu = s * (1.f / 1024.f);
    const float var = sq * (1.f / 1024.f) - mu * mu;
    const float rstd = rsqrtf(var + 1e-5f);
    float4 gv = *(const float4*)(g + tid * 4);
    float4 bv = *(const float4*)(be + tid * 4);
    float o0 = (v0 - mu) * rstd * gv.x + bv.x;
    float o1 = (v1 - mu) * rstd * gv.y + bv.y;
    float o2 = (v2 - mu) * rstd * gv.z + bv.z;
    float o3 = (v3 - mu) * rstd * gv.w + bv.w;
    if (outf) {
        float4 ov = {o0, o1, o2, o3};
        *(float4*)(outf + base) = ov;
    }
    if (outb) {
        bf16x4 ob;
        ob[0] = (bf16_t)o0; ob[1] = (bf16_t)o1; ob[2] = (bf16_t)o2; ob[3] = (bf16_t)o3;
        *(bf16x4*)(outb + base) = ob;
    }
}

// ---------------- host launch ----------------
extern "C" void kernel_launch(void* const* d_in, const int* in_sizes, int n_in,
                              void* d_out, int out_size, void* d_ws, size_t ws_size,
                              hipStream_t stream) {
    (void)in_sizes; (void)n_in; (void)out_size; (void)ws_size;
    const float* x   = (const float*)d_in[0];
    const float* Wq  = (const float*)d_in[1];
    const float* bq  = (const float*)d_in[2];
    const float* Wk  = (const float*)d_in[3];
    const float* bk  = (const float*)d_in[4];
    const float* Wv  = (const float*)d_in[5];
    const float* bv  = (const float*)d_in[6];
    const float* Wo  = (const float*)d_in[7];
    const float* bo  = (const float*)d_in[8];
    const float* g1  = (const float*)d_in[9];
    const float* b1  = (const float*)d_in[10];
    const float* W1  = (const float*)d_in[11];
    const float* bb1 = (const float*)d_in[12];
    const float* W2  = (const float*)d_in[13];
    const float* bb2 = (const float*)d_in[14];
    const float* g2  = (const float*)d_in[15];
    const float* b2  = (const float*)d_in[16];
    float* out = (float*)d_out;

    char* ws = (char*)d_ws;
    const size_t MB = 1ull << 20;
    bf16_t* xb    = (bf16_t*)(ws + 0);         // 8 MB  [4096][1024]
    bf16_t* WqkvT = (bf16_t*)(ws + 8 * MB);    // 6 MB  [3072][1024]
    bf16_t* WoT   = (bf16_t*)(ws + 14 * MB);   // 2 MB  [1024][1024]
    bf16_t* W1T   = (bf16_t*)(ws + 16 * MB);   // 8 MB  [4096][1024]
    bf16_t* W2T   = (bf16_t*)(ws + 24 * MB);   // 8 MB  [1024][4096]
    float*  qkvb  = (float*)(ws + 32 * MB);    // 12 KB
    float*  lpart = (float*)(ws + 32 * MB + 64 * 1024);   // 512 KB [2][32][2048]
    bf16_t* QKV   = (bf16_t*)(ws + 33 * MB);   // 24 MB [4096][3072]    (dead after attn)
    bf16_t* VTh   = (bf16_t*)(ws + 57 * MB);   // 8 MB  [32][64][2048]  (dead after attn)
    bf16_t* Otok  = (bf16_t*)(ws + 65 * MB);   // 8 MB  [4096][1024]    (dead after Wo gemm)
    float*  Opart = (float*)(ws + 73 * MB);    // 32 MB [2][4096][1024] f32 (dead after combine)
    bf16_t* WoP   = (bf16_t*)(ws + 73 * MB);   // 32 MB [4][4096][1024] bf16 (written after combine; dead after ln1)
    bf16_t* x1b   = (bf16_t*)(ws + 105 * MB);  // 8 MB
    bf16_t* Hff   = (bf16_t*)(ws + 113 * MB);  // 32 MB [4096][4096]
    bf16_t* W2P   = (bf16_t*)(ws + 33 * MB);   // 32 MB [4][4096][1024] bf16 (reuses QKV/VTh region)

    // fused prep (one launch): weight transposes + x cast + bias concat
    prep_all<<<7180, 256, 0, stream>>>(x, Wq, Wk, Wv, Wo, W1, W2, bq, bk, bv,
                                       xb, WqkvT, WoT, W1T, W2T, qkvb);

    // attention path
    gemm256<0, false><<<192, 512, 0, stream>>>(xb, WqkvT, qkvb, QKV, 4096, 3072, 1024, 1024, 1);
    reshape_v<<<1024, 256, 0, stream>>>(QKV, VTh);
    attn_fwd<<<1024, 256, 0, stream>>>(QKV, VTh, Opart, lpart);
    combine_o<<<4096, 256, 0, stream>>>(Opart, lpart, Otok);
    gemm256<2, false><<<256, 512, 0, stream>>>(Otok, WoT, bo, WoP, 4096, 1024, 1024, 256, 4);
    ln_res<4><<<4096, 256, 0, stream>>>(xb, WoP, g1, b1, nullptr, x1b);

    // FFN path
    gemm256<0, true><<<256, 512, 0, stream>>>(x1b, W1T, bb1, Hff, 4096, 4096, 1024, 1024, 1);
    gemm256<2, false><<<256, 512, 0, stream>>>(Hff, W2T, bb2, W2P, 4096, 1024, 4096, 1024, 4);
    ln_res<4><<<4096, 256, 0, stream>>>(x1b, W2P, g2, b2, out, nullptr);
}

// Round 15
// 225.664 us; speedup vs baseline: 1.0436x; 1.0436x over previous
//
#include <hip/hip_runtime.h>
#include <hip/hip_bf16.h>
#include <cstdint>

typedef __bf16 bf16_t;
typedef __attribute__((ext_vector_type(8))) __bf16 bf16x8;
typedef __attribute__((ext_vector_type(4))) __bf16 bf16x4;
typedef __attribute__((ext_vector_type(2))) __bf16 bf16x2;
typedef __attribute__((ext_vector_type(4))) float f32x4;

#define GLOBAL_AS __attribute__((address_space(1)))
#define LDS_AS __attribute__((address_space(3)))

__device__ __forceinline__ void lds_load16(void* lds, const void* g) {
    __builtin_amdgcn_global_load_lds((GLOBAL_AS void*)g, (LDS_AS void*)lds, 16, 0, 0);
}

// ---------------- fused prep: weight transposes + x cast + bias concat ----------------
__global__ __launch_bounds__(256) void prep_all(const float* __restrict__ x,
                                                const float* __restrict__ Wq,
                                                const float* __restrict__ Wk,
                                                const float* __restrict__ Wv,
                                                const float* __restrict__ Wo,
                                                const float* __restrict__ W1,
                                                const float* __restrict__ W2,
                                                const float* __restrict__ bq,
                                                const float* __restrict__ bk,
                                                const float* __restrict__ bv,
                                                bf16_t* __restrict__ xb,
                                                bf16_t* __restrict__ WqkvT,
                                                bf16_t* __restrict__ WoT,
                                                bf16_t* __restrict__ W1T,
                                                bf16_t* __restrict__ W2T,
                                                float* __restrict__ qkvb) {
    __shared__ float T[64][65];
    const int bid = blockIdx.x, tid = threadIdx.x;
    if (bid < 3072) {
        const float* W; bf16_t* WT; int Kd, Nd, lb;
        if (bid < 1024) {
            Kd = 1024; Nd = 1024; lb = bid & 255;
            const int w = bid >> 8;
            W  = (w == 0) ? Wq : (w == 1) ? Wk : (w == 2) ? Wv : Wo;
            WT = (w == 0) ? WqkvT : (w == 1) ? WqkvT + 1048576
               : (w == 2) ? WqkvT + 2097152 : WoT;
        } else if (bid < 2048) { W = W1; WT = W1T; Kd = 1024; Nd = 4096; lb = bid - 1024; }
        else                   { W = W2; WT = W2T; Kd = 4096; Nd = 1024; lb = bid - 2048; }
        const int nbk = Kd >> 6;
        const int bk = lb % nbk, bn = lb / nbk;
        const int k0 = bk << 6, n0 = bn << 6;
        #pragma unroll
        for (int rep = 0; rep < 4; ++rep) {
            int r = rep * 16 + (tid >> 4);
            int c = (tid & 15) * 4;
            float4 v = *(const float4*)(W + (size_t)(k0 + r) * Nd + n0 + c);
            T[r][c] = v.x; T[r][c + 1] = v.y; T[r][c + 2] = v.z; T[r][c + 3] = v.w;
        }
        __syncthreads();
        #pragma unroll
        for (int rep = 0; rep < 4; ++rep) {
            int r = rep * 16 + (tid >> 4);   // n-local
            int c = (tid & 15) * 4;          // k-local
            bf16x4 o;
            o[0] = (bf16_t)T[c][r]; o[1] = (bf16_t)T[c + 1][r];
            o[2] = (bf16_t)T[c + 2][r]; o[3] = (bf16_t)T[c + 3][r];
            *(bf16x4*)(WT + (size_t)(n0 + r) * Kd + k0 + c) = o;
        }
    } else if (bid < 7168) {
        const int i = (bid - 3072) * 256 + tid;   // < 1048576
        float4 v = *(const float4*)(x + (size_t)i * 4);
        bf16x4 o;
        o[0] = (bf16_t)v.x; o[1] = (bf16_t)v.y; o[2] = (bf16_t)v.z; o[3] = (bf16_t)v.w;
        *(bf16x4*)(xb + (size_t)i * 4) = o;
    } else {
        const int i = (bid - 7168) * 256 + tid;
        if (i < 3072)
            qkvb[i] = (i < 1024) ? bq[i] : (i < 2048) ? bk[i - 1024] : bv[i - 2048];
    }
}

// ---------------- 256x256 phase-split GEMM: C = A[M][K] @ Bt[N][K]^T + bias ----------------
// BM=BN=256, BK=64, 8 waves. Counted-vmcnt ledger (see round-5 comment).
// OM: 0 = bf16 full output, 1 = f32 split-K partials, 2 = bf16 split-K partials.
template <int OM, bool RELU>
__global__ __launch_bounds__(512, 2) void gemm256(const bf16_t* __restrict__ A,
                                                  const bf16_t* __restrict__ Bt,
                                                  const float* __restrict__ bias,
                                                  void* __restrict__ Cv,
                                                  int M, int N, int K,
                                                  int kc_len, int n_kc) {
    __shared__ alignas(16) bf16_t As[2][256 * 64];
    __shared__ alignas(16) bf16_t Bs[2][256 * 64];
    const int tid = threadIdx.x;
    const int wid = tid >> 6, lane = tid & 63;
    const int lr = lane & 15, lg = lane >> 4;
    const int wr = wid >> 2, wc = wid & 3;
    const int lrsw = (lr & 7) << 4;

    const int nbn = N >> 8;
    const int nbase = (M >> 8) * nbn;
    const int nwg = nbase * n_kc;
    int bid = blockIdx.x;
    int wg;
    if ((nwg & 7) == 0) { int q = nwg >> 3; wg = (bid & 7) * q + (bid >> 3); }
    else wg = bid;
    const int kc = wg / nbase;
    const int inner = wg - kc * nbase;
    const int bm = inner / nbn, bn = inner % nbn;

    f32x4 acc[8][4];
    #pragma unroll
    for (int i = 0; i < 8; ++i)
        #pragma unroll
        for (int j = 0; j < 4; ++j) acc[i][j] = f32x4{0.f, 0.f, 0.f, 0.f};

    const int srow = wid * 16 + (lane >> 3);
    const int colbyte = (((lane & 7) ^ (lane >> 3)) << 4);
    const char* gA = (const char*)(A + ((size_t)(bm * 256 + srow) * K + kc * kc_len)) + colbyte;
    const char* gB = (const char*)(Bt + ((size_t)(bn * 256 + srow) * K + kc * kc_len)) + colbyte;
    const size_t rs8 = (size_t)8 * K * 2;
    const size_t rs128 = (size_t)128 * K * 2;

    auto stA = [&](int b, int half, int kt) {
        char* d = (char*)As[b] + (half * 128 + wid * 16) * 128;
        const char* s = gA + (size_t)half * rs128 + (size_t)kt * 128;
        lds_load16(d, s);
        lds_load16(d + 1024, s + rs8);
    };
    auto stB = [&](int b, int half, int kt) {
        char* d = (char*)Bs[b] + (half * 128 + wid * 16) * 128;
        const char* s = gB + (size_t)half * rs128 + (size_t)kt * 128;
        lds_load16(d, s);
        lds_load16(d + 1024, s + rs8);
    };
    auto ldA = [&](int b, int m, int kk) {
        const int row = (m >> 2) * 128 + (m & 3) * 32 + wr * 16 + lr;
        return *(const bf16x8*)((const char*)As[b] + row * 128 + ((kk * 64 + lg * 16) ^ lrsw));
    };
    auto ldB = [&](int b, int n, int kk) {
        const int row = n * 64 + wc * 16 + lr;
        return *(const bf16x8*)((const char*)Bs[b] + row * 128 + ((kk * 64 + lg * 16) ^ lrsw));
    };

    const int NT = kc_len >> 6;
    stA(0, 0, 0); stB(0, 0, 0); stB(0, 1, 0); stA(0, 1, 0);
    asm volatile("s_waitcnt vmcnt(4)" ::: "memory");
    __builtin_amdgcn_s_barrier();

    bf16x8 afr[4][2], bfr[4][2];
    #pragma unroll 1
    for (int kt = 0; kt < NT; ++kt) {
        const int buf = kt & 1;
        const int ktn = (kt + 1 < NT) ? kt + 1 : kt;

        // ---- phase 0: (0,0); reads A-half0 + B n0,n1 ----
        #pragma unroll
        for (int m = 0; m < 4; ++m) {
            afr[m][0] = ldA(buf, m, 0);
            afr[m][1] = ldA(buf, m, 1);
        }
        #pragma unroll
        for (int n = 0; n < 2; ++n) {
            bfr[n][0] = ldB(buf, n, 0);
            bfr[n][1] = ldB(buf, n, 1);
        }
        stA(buf ^ 1, 0, ktn);
        __builtin_amdgcn_s_barrier();
        __builtin_amdgcn_s_setprio(1);
        #pragma unroll
        for (int m = 0; m < 4; ++m)
            #pragma unroll
            for (int n = 0; n < 2; ++n) {
                acc[m][n] = __builtin_amdgcn_mfma_f32_16x16x32_bf16(afr[m][0], bfr[n][0], acc[m][n], 0, 0, 0);
                acc[m][n] = __builtin_amdgcn_mfma_f32_16x16x32_bf16(afr[m][1], bfr[n][1], acc[m][n], 0, 0, 0);
            }
        __builtin_amdgcn_s_setprio(0);
        asm volatile("s_waitcnt vmcnt(4)" ::: "memory");
        __builtin_amdgcn_s_barrier();

        // ---- phase 1: (0,1); reads B n2,n3 ----
        #pragma unroll
        for (int n = 2; n < 4; ++n) {
            bfr[n][0] = ldB(buf, n, 0);
            bfr[n][1] = ldB(buf, n, 1);
        }
        stB(buf ^ 1, 0, ktn);
        __builtin_amdgcn_s_barrier();
        __builtin_amdgcn_s_setprio(1);
        #pragma unroll
        for (int m = 0; m < 4; ++m)
            #pragma unroll
            for (int n = 2; n < 4; ++n) {
                acc[m][n] = __builtin_amdgcn_mfma_f32_16x16x32_bf16(afr[m][0], bfr[n][0], acc[m][n], 0, 0, 0);
                acc[m][n] = __builtin_amdgcn_mfma_f32_16x16x32_bf16(afr[m][1], bfr[n][1], acc[m][n], 0, 0, 0);
            }
        __builtin_amdgcn_s_setprio(0);
        asm volatile("s_waitcnt vmcnt(4)" ::: "memory");
        __builtin_amdgcn_s_barrier();

        // ---- phase 2: (1,0); reads A-half1 ----
        #pragma unroll
        for (int m = 0; m < 4; ++m) {
            afr[m][0] = ldA(buf, m + 4, 0);
            afr[m][1] = ldA(buf, m + 4, 1);
        }
        stB(buf ^ 1, 1, ktn);
        __builtin_amdgcn_s_barrier();
        __builtin_amdgcn_s_setprio(1);
        #pragma unroll
        for (int m = 0; m < 4; ++m)
            #pragma unroll
            for (int n = 0; n < 2; ++n) {
                acc[m + 4][n] = __builtin_amdgcn_mfma_f32_16x16x32_bf16(afr[m][0], bfr[n][0], acc[m + 4][n], 0, 0, 0);
                acc[m + 4][n] = __builtin_amdgcn_mfma_f32_16x16x32_bf16(afr[m][1], bfr[n][1], acc[m + 4][n], 0, 0, 0);
            }
        __builtin_amdgcn_s_setprio(0);
        __builtin_amdgcn_s_barrier();

        // ---- phase 3: (1,1) ----
        stA(buf ^ 1, 1, ktn);
        __builtin_amdgcn_s_barrier();
        __builtin_amdgcn_s_setprio(1);
        #pragma unroll
        for (int m = 0; m < 4; ++m)
            #pragma unroll
            for (int n = 2; n < 4; ++n) {
                acc[m + 4][n] = __builtin_amdgcn_mfma_f32_16x16x32_bf16(afr[m][0], bfr[n][0], acc[m + 4][n], 0, 0, 0);
                acc[m + 4][n] = __builtin_amdgcn_mfma_f32_16x16x32_bf16(afr[m][1], bfr[n][1], acc[m + 4][n], 0, 0, 0);
            }
        __builtin_amdgcn_s_setprio(0);
        asm volatile("s_waitcnt vmcnt(4)" ::: "memory");
        __builtin_amdgcn_s_barrier();
    }

    // epilogue
    float* outf = (float*)Cv + (size_t)kc * M * N;
    bf16_t* outb = (bf16_t*)Cv + (size_t)kc * M * N;
    float bv[4];
    #pragma unroll
    for (int n = 0; n < 4; ++n) {
        const int c = (bn << 8) + n * 64 + wc * 16 + lr;
        bv[n] = (bias && kc == 0) ? bias[c] : 0.f;
    }
    #pragma unroll
    for (int m = 0; m < 8; ++m) {
        const int row0 = (bm << 8) + (m >> 2) * 128 + (m & 3) * 32 + wr * 16 + (lg << 2);
        #pragma unroll
        for (int n = 0; n < 4; ++n) {
            const int c = (bn << 8) + n * 64 + wc * 16 + lr;
            #pragma unroll
            for (int j = 0; j < 4; ++j) {
                float v = acc[m][n][j] + bv[n];
                if (RELU) v = fmaxf(v, 0.f);
                if (OM == 0)      ((bf16_t*)Cv)[(size_t)(row0 + j) * N + c] = (bf16_t)v;
                else if (OM == 1) outf[(size_t)(row0 + j) * N + c] = v;
                else              outb[(size_t)(row0 + j) * N + c] = (bf16_t)v;
            }
        }
    }
}

// ---------------- V-transpose only: QKV[4096][3072] V-part -> VT [32][64][2048] ----------------
__global__ __launch_bounds__(256) void reshape_v(const bf16_t* __restrict__ QKV,
                                                 bf16_t* __restrict__ VT) {
    __shared__ alignas(16) bf16_t Vl[64][72];
    const int n = blockIdx.x >> 5, st = blockIdx.x & 31;
    const int b = n >> 4, h = n & 15;
    const int s0 = st << 6;
    const int tid = threadIdx.x;

    #pragma unroll
    for (int rep = 0; rep < 2; ++rep) {
        int chunk = rep * 256 + tid;
        int sl = chunk >> 3, c8 = (chunk & 7) << 3;
        size_t srow = (size_t)(s0 + sl) * 2 + b;
        *(bf16x8*)&Vl[sl][c8] = *(const bf16x8*)(QKV + srow * 3072 + 2048 + h * 64 + c8);
    }
    __syncthreads();
    #pragma unroll
    for (int rep = 0; rep < 2; ++rep) {
        int chunk = rep * 256 + tid;
        int d = chunk >> 3, c8 = (chunk & 7) << 3;
        bf16x8 v;
        #pragma unroll
        for (int e = 0; e < 8; ++e) v[e] = Vl[c8 + e][d];
        *(bf16x8*)(VT + ((size_t)n * 64 + d) * 2048 + s0 + c8) = v;
    }
}

// ---------------- flash attention: 32 q-rows/wave (2 q-groups), constant-shift softmax ----------------
// Round-13 proven configuration: K/V LDS dbuf, stage(next) BEFORE vmcnt(4),
// two barriers/tile, b64 P-writes, setprio around MFMA clusters, constant
// shift m=12 folded into QK acc init, l via ones-row MFMA, Q/K direct from QKV.
__global__ __launch_bounds__(256) void attn_fwd(const bf16_t* __restrict__ QKV,
                                                const bf16_t* __restrict__ VT,
                                                bf16_t* __restrict__ O) {
    const int S = 2048;
    const int n = blockIdx.x >> 4;       // b*16 + h
    const int qt = blockIdx.x & 15;
    const int q0 = qt << 7;              // 128 q-rows per block
    const int b = n >> 4, h = n & 15;
    const int tid = threadIdx.x, wid = tid >> 6, lane = tid & 63;
    const int lr = lane & 15, lg = lane >> 4;
    const int lrsw = (lr & 7) << 4;

    __shared__ alignas(16) bf16_t Ks[2][64 * 64];
    __shared__ alignas(16) bf16_t Vs[2][64 * 64];
    __shared__ alignas(16) bf16_t Ps[4][2][16 * 64];

    char* pbs0 = (char*)&Ps[wid][0][0];
    char* pbs1 = (char*)&Ps[wid][1][0];

    // Q fragments straight from QKV (token-major), scaled in registers
    const float qsc = 0.125f * 1.4426950408889634f;
    auto scale8 = [&](bf16x8 v) {
        bf16x8 r;
        #pragma unroll
        for (int e = 0; e < 8; ++e) r[e] = (bf16_t)((float)v[e] * qsc);
        return r;
    };
    const bf16_t* Qrow0 = QKV + ((size_t)(q0 + wid * 32 + lr) * 2 + b) * 3072 + h * 64;
    const bf16_t* Qrow1 = Qrow0 + (size_t)16 * 2 * 3072;
    const bf16x8 qa0 = scale8(*(const bf16x8*)(Qrow0 + lg * 8));
    const bf16x8 qa1 = scale8(*(const bf16x8*)(Qrow0 + 32 + lg * 8));
    const bf16x8 qb0 = scale8(*(const bf16x8*)(Qrow1 + lg * 8));
    const bf16x8 qb1 = scale8(*(const bf16x8*)(Qrow1 + 32 + lg * 8));

    bf16x8 ones;
    #pragma unroll
    for (int e = 0; e < 8; ++e) ones[e] = (bf16_t)1.0f;

    const int colbyte = (((lane & 7) ^ (lane >> 3)) << 4);
    // K source in QKV: row t at byte stride 2*3072*2 = 12288
    const size_t kstride = (size_t)2 * 3072 * 2;
    const char* ksrc0 = (const char*)QKV +
        (((size_t)(wid * 16 + (lane >> 3)) * 2 + b) * 3072 + 1024 + h * 64) * 2 + colbyte;
    const char* ksrc1 = ksrc0 + 8 * kstride;
    const char* vsrc0 = (const char*)(VT + ((size_t)n * 64 + wid * 16 + (lane >> 3)) * S) + colbyte;
    const char* vsrc1 = vsrc0 + (size_t)8 * S * 2;

    auto stage = [&](int bf, int t0) {
        lds_load16((char*)Ks[bf] + wid * 2048,        ksrc0 + (size_t)t0 * kstride);
        lds_load16((char*)Ks[bf] + wid * 2048 + 1024, ksrc1 + (size_t)t0 * kstride);
        lds_load16((char*)Vs[bf] + wid * 2048,        vsrc0 + (size_t)t0 * 2);
        lds_load16((char*)Vs[bf] + wid * 2048 + 1024, vsrc1 + (size_t)t0 * 2);
    };

    f32x4 oaccA[4], oaccB[4];
    #pragma unroll
    for (int i = 0; i < 4; ++i) {
        oaccA[i] = f32x4{0.f, 0.f, 0.f, 0.f};
        oaccB[i] = f32x4{0.f, 0.f, 0.f, 0.f};
    }
    f32x4 laccA = f32x4{0.f, 0.f, 0.f, 0.f};
    f32x4 laccB = f32x4{0.f, 0.f, 0.f, 0.f};

    stage(0, 0);
    int buf = 0;

    #pragma unroll 1
    for (int t0 = 0; t0 < S; t0 += 64) {
        if (t0 + 64 < S) {
            stage(buf ^ 1, t0 + 64);
            asm volatile("s_waitcnt vmcnt(4)" ::: "memory");
        } else {
            asm volatile("s_waitcnt vmcnt(0)" ::: "memory");
        }
        __builtin_amdgcn_s_barrier();

        const char* kb = (char*)Ks[buf];
        const char* vb = (char*)Vs[buf];

        // S^T tiles for both q-groups; K-frags loaded once, used twice
        f32x4 swA[4], swB[4];
        __builtin_amdgcn_s_setprio(1);
        #pragma unroll
        for (int tc = 0; tc < 4; ++tc) {
            const char* krow = kb + (tc * 16 + lr) * 128;
            bf16x8 kf0 = *(const bf16x8*)(krow + ((lg * 16) ^ lrsw));
            bf16x8 kf1 = *(const bf16x8*)(krow + ((64 + lg * 16) ^ lrsw));
            f32x4 za = f32x4{-12.f, -12.f, -12.f, -12.f};
            za = __builtin_amdgcn_mfma_f32_16x16x32_bf16(kf0, qa0, za, 0, 0, 0);
            za = __builtin_amdgcn_mfma_f32_16x16x32_bf16(kf1, qa1, za, 0, 0, 0);
            swA[tc] = za;
            f32x4 zb = f32x4{-12.f, -12.f, -12.f, -12.f};
            zb = __builtin_amdgcn_mfma_f32_16x16x32_bf16(kf0, qb0, zb, 0, 0, 0);
            zb = __builtin_amdgcn_mfma_f32_16x16x32_bf16(kf1, qb1, zb, 0, 0, 0);
            swB[tc] = zb;
        }
        __builtin_amdgcn_s_setprio(0);

        // P = exp2(shifted score), both groups (independent chains)
        #pragma unroll
        for (int tc = 0; tc < 4; ++tc)
            #pragma unroll
            for (int j = 0; j < 4; ++j) {
                swA[tc][j] = __builtin_amdgcn_exp2f(swA[tc][j]);
                swB[tc][j] = __builtin_amdgcn_exp2f(swB[tc][j]);
            }

        // pack P^T into per-wave-per-group LDS (swizzled), b64 writes
        #pragma unroll
        for (int tc = 0; tc < 4; ++tc) {
            bf16x4 pa, pb;
            pa[0] = (bf16_t)swA[tc][0]; pa[1] = (bf16_t)swA[tc][1];
            pa[2] = (bf16_t)swA[tc][2]; pa[3] = (bf16_t)swA[tc][3];
            pb[0] = (bf16_t)swB[tc][0]; pb[1] = (bf16_t)swB[tc][1];
            pb[2] = (bf16_t)swB[tc][2]; pb[3] = (bf16_t)swB[tc][3];
            const int off = (tc * 32 + lg * 8) ^ lrsw;
            *(bf16x4*)(pbs0 + lr * 128 + off) = pa;
            *(bf16x4*)(pbs1 + lr * 128 + off) = pb;
        }
        bf16x8 pA0 = *(const bf16x8*)(pbs0 + lr * 128 + ((lg * 16) ^ lrsw));
        bf16x8 pA1 = *(const bf16x8*)(pbs0 + lr * 128 + ((64 + lg * 16) ^ lrsw));
        bf16x8 pB0 = *(const bf16x8*)(pbs1 + lr * 128 + ((lg * 16) ^ lrsw));
        bf16x8 pB1 = *(const bf16x8*)(pbs1 + lr * 128 + ((64 + lg * 16) ^ lrsw));

        // l row-sums + PV on the MFMA pipe (setprio cluster)
        __builtin_amdgcn_s_setprio(1);
        laccA = __builtin_amdgcn_mfma_f32_16x16x32_bf16(ones, pA0, laccA, 0, 0, 0);
        laccA = __builtin_amdgcn_mfma_f32_16x16x32_bf16(ones, pA1, laccA, 0, 0, 0);
        laccB = __builtin_amdgcn_mfma_f32_16x16x32_bf16(ones, pB0, laccB, 0, 0, 0);
        laccB = __builtin_amdgcn_mfma_f32_16x16x32_bf16(ones, pB1, laccB, 0, 0, 0);

        // O^T += V^T @ P^T ; V-frags loaded once, used by both groups
        #pragma unroll
        for (int vc = 0; vc < 4; ++vc) {
            const char* vrow = vb + (vc * 16 + lr) * 128;
            bf16x8 vf0 = *(const bf16x8*)(vrow + ((lg * 16) ^ lrsw));
            bf16x8 vf1 = *(const bf16x8*)(vrow + ((64 + lg * 16) ^ lrsw));
            oaccA[vc] = __builtin_amdgcn_mfma_f32_16x16x32_bf16(vf0, pA0, oaccA[vc], 0, 0, 0);
            oaccA[vc] = __builtin_amdgcn_mfma_f32_16x16x32_bf16(vf1, pA1, oaccA[vc], 0, 0, 0);
            oaccB[vc] = __builtin_amdgcn_mfma_f32_16x16x32_bf16(vf0, pB0, oaccB[vc], 0, 0, 0);
            oaccB[vc] = __builtin_amdgcn_mfma_f32_16x16x32_bf16(vf1, pB1, oaccB[vc], 0, 0, 0);
        }
        __builtin_amdgcn_s_setprio(0);
        __builtin_amdgcn_s_barrier();
        buf ^= 1;
    }

    const float invA = 1.0f / laccA[0];
    const float invB = 1.0f / laccB[0];
    const size_t tokA = (size_t)(q0 + wid * 32 + lr) * 2 + b;
    const size_t tokB = tokA + 32;      // +16 q-rows * 2
    #pragma unroll
    for (int vc = 0; vc < 4; ++vc) {
        bf16x4 oa, ob;
        #pragma unroll
        for (int j = 0; j < 4; ++j) {
            oa[j] = (bf16_t)(oaccA[vc][j] * invA);
            ob[j] = (bf16_t)(oaccB[vc][j] * invB);
        }
        *(bf16x4*)(O + tokA * 1024 + h * 64 + vc * 16 + lg * 4) = oa;
        *(bf16x4*)(O + tokB * 1024 + h * 64 + vc * 16 + lg * 4) = ob;
    }
}

// ---------------- residual + LayerNorm: out = LN(X + sum_p Y_p)*g + b ----------------
// X is bf16 (residual path); partials Y are bf16 (written by gemm256 OM=2).
template <int P>
__global__ __launch_bounds__(256) void ln_res(const bf16_t* __restrict__ X,
                                              const bf16_t* __restrict__ Y,
                                              const float* __restrict__ g,
                                              const float* __restrict__ be,
                                              float* __restrict__ outf,
                                              bf16_t* __restrict__ outb) {
    const int row = blockIdx.x, tid = threadIdx.x;
    const size_t base = (size_t)row * 1024 + tid * 4;
    const size_t pstride = (size_t)4096 * 1024;
    bf16x4 xv = *(const bf16x4*)(X + base);
    float v0 = (float)xv[0], v1 = (float)xv[1], v2 = (float)xv[2], v3 = (float)xv[3];
    #pragma unroll
    for (int p = 0; p < P; ++p) {
        bf16x4 yv = *(const bf16x4*)(Y + p * pstride + base);
        v0 += (float)yv[0]; v1 += (float)yv[1]; v2 += (float)yv[2]; v3 += (float)yv[3];
    }
    float s = v0 + v1 + v2 + v3;
    float sq = v0 * v0 + v1 * v1 + v2 * v2 + v3 * v3;
    #pragma unroll
    for (int m = 1; m < 64; m <<= 1) {
        s += __shfl_xor(s, m);
        sq += __shfl_xor(sq, m);
    }
    __shared__ float rs[4], rq[4];
    const int wid = tid >> 6;
    if ((tid & 63) == 0) { rs[wid] = s; rq[wid] = sq; }
    __syncthreads();
    s = rs[0] + rs[1] + rs[2] + rs[3];
    sq = rq[0] + rq[1] + rq[2] + rq[3];
    const float mu = s * (1.f / 1024.f);
    const float var = sq * (1.f / 1024.f) - mu * mu;
    const float rstd = rsqrtf(var + 1e-5f);
    float4 gv = *(const float4*)(g + tid * 4);
    float4 bv = *(const float4*)(be + tid * 4);
    float o0 = (v0 - mu) * rstd * gv.x + bv.x;
    float o1 = (v1 - mu) * rstd * gv.y + bv.y;
    float o2 = (v2 - mu) * rstd * gv.z + bv.z;
    float o3 = (v3 - mu) * rstd * gv.w + bv.w;
    if (outf) {
        float4 ov = {o0, o1, o2, o3};
        *(float4*)(outf + base) = ov;
    }
    if (outb) {
        bf16x4 ob;
        ob[0] = (bf16_t)o0; ob[1] = (bf16_t)o1; ob[2] = (bf16_t)o2; ob[3] = (bf16_t)o3;
        *(bf16x4*)(outb + base) = ob;
    }
}

// ---------------- host launch ----------------
extern "C" void kernel_launch(void* const* d_in, const int* in_sizes, int n_in,
                              void* d_out, int out_size, void* d_ws, size_t ws_size,
                              hipStream_t stream) {
    (void)in_sizes; (void)n_in; (void)out_size; (void)ws_size;
    const float* x   = (const float*)d_in[0];
    const float* Wq  = (const float*)d_in[1];
    const float* bq  = (const float*)d_in[2];
    const float* Wk  = (const float*)d_in[3];
    const float* bk  = (const float*)d_in[4];
    const float* Wv  = (const float*)d_in[5];
    const float* bv  = (const float*)d_in[6];
    const float* Wo  = (const float*)d_in[7];
    const float* bo  = (const float*)d_in[8];
    const float* g1  = (const float*)d_in[9];
    const float* b1  = (const float*)d_in[10];
    const float* W1  = (const float*)d_in[11];
    const float* bb1 = (const float*)d_in[12];
    const float* W2  = (const float*)d_in[13];
    const float* bb2 = (const float*)d_in[14];
    const float* g2  = (const float*)d_in[15];
    const float* b2  = (const float*)d_in[16];
    float* out = (float*)d_out;

    char* ws = (char*)d_ws;
    const size_t MB = 1ull << 20;
    bf16_t* xb    = (bf16_t*)(ws + 0);         // 8 MB  [4096][1024]
    bf16_t* WqkvT = (bf16_t*)(ws + 8 * MB);    // 6 MB  [3072][1024]
    bf16_t* WoT   = (bf16_t*)(ws + 14 * MB);   // 2 MB  [1024][1024]
    bf16_t* W1T   = (bf16_t*)(ws + 16 * MB);   // 8 MB  [4096][1024]
    bf16_t* W2T   = (bf16_t*)(ws + 24 * MB);   // 8 MB  [1024][4096]
    float*  qkvb  = (float*)(ws + 32 * MB);    // 12 KB
    bf16_t* QKV   = (bf16_t*)(ws + 33 * MB);   // 24 MB [4096][3072]    (dead after attn)
    bf16_t* VTh   = (bf16_t*)(ws + 57 * MB);   // 8 MB  [32][64][2048]  (dead after attn)
    bf16_t* Otok  = (bf16_t*)(ws + 65 * MB);   // 8 MB  [4096][1024]    (dead after Wo gemm)
    bf16_t* WoP   = (bf16_t*)(ws + 73 * MB);   // 32 MB [4][4096][1024] bf16 (dead after ln1)
    bf16_t* x1b   = (bf16_t*)(ws + 105 * MB);  // 8 MB
    bf16_t* Hff   = (bf16_t*)(ws + 113 * MB);  // 32 MB [4096][4096]
    bf16_t* W2P   = (bf16_t*)(ws + 33 * MB);   // 32 MB [4][4096][1024] bf16 (reuses QKV/VTh region)

    // fused prep (one launch): weight transposes + x cast + bias concat
    prep_all<<<7180, 256, 0, stream>>>(x, Wq, Wk, Wv, Wo, W1, W2, bq, bk, bv,
                                       xb, WqkvT, WoT, W1T, W2T, qkvb);

    // attention path
    gemm256<0, false><<<192, 512, 0, stream>>>(xb, WqkvT, qkvb, QKV, 4096, 3072, 1024, 1024, 1);
    reshape_v<<<1024, 256, 0, stream>>>(QKV, VTh);
    attn_fwd<<<512, 256, 0, stream>>>(QKV, VTh, Otok);
    gemm256<2, false><<<256, 512, 0, stream>>>(Otok, WoT, bo, WoP, 4096, 1024, 1024, 256, 4);
    ln_res<4><<<4096, 256, 0, stream>>>(xb, WoP, g1, b1, nullptr, x1b);

    // FFN path
    gemm256<0, true><<<256, 512, 0, stream>>>(x1b, W1T, bb1, Hff, 4096, 4096, 1024, 1024, 1);
    gemm256<2, false><<<256, 512, 0, stream>>>(Hff, W2T, bb2, W2P, 4096, 1024, 4096, 1024, 4);
    ln_res<4><<<4096, 256, 0, stream>>>(x1b, W2P, g2, b2, out, nullptr);
}